// Round 14
// baseline (144.620 us; speedup 1.0000x reference)
//
#include <hip/hip_runtime.h>
#include <hip/hip_bf16.h>

typedef __attribute__((ext_vector_type(8))) short short8;
typedef __attribute__((ext_vector_type(4))) int   i32x4;
typedef __attribute__((ext_vector_type(4))) float f32x4;
typedef __attribute__((ext_vector_type(2))) float f32x2;
typedef __attribute__((ext_vector_type(8))) float f32x8;

constexpr int BATCH  = 4;
constexpr int NSRC   = 2048;
constexpr int NTGT   = 8192;
constexpr int C_IN   = 256;
constexpr int C_SKIP = 128;
constexpr int DIN    = 384;   // C_IN + C_SKIP
constexpr int HID    = 256;
constexpr int MROWS  = BATCH * NTGT;  // 32768

constexpr int TGT_PER_BLK = 16;
constexpr int KNN_BLOCKS  = MROWS / TGT_PER_BLK;  // 2048
constexpr int WT_BLOCKS   = 8;                    // W1 transpose helper blocks
constexpr int LDS_STRIDE  = 36;                   // GEMM A-tile pad

__device__ __forceinline__ short f2bf(float v) {
    __hip_bfloat16 h = __float2bfloat16(v);
    return (short)__builtin_bit_cast(unsigned short, h);
}
__device__ __forceinline__ float bf2f(short s) {
    return __uint_as_float(((unsigned)(unsigned short)s) << 16);
}

// ================= KNN: two-pass, dual value-chains + recompute pass 2 =================
// Pass 1: exact distances (packed f32, reference op order); TWO independent min/med3 chains
// (j1-half / j2-half) halve the serial dependence; merge sorted triples; value butterfly ->
// cutoff a2. Pass 2: recompute distances (bitwise-identical), wave-uniform __any skip, exact
// lex insert on hits (junk from non-hit lanes > a2 provably never survives; butterfly stays
// within each 32-lane target). launch_bounds(512,8): 4 blocks/CU (R13 counters: Occ 37%,
// VALUBusy 68% -> latency-exposed at 2 blocks/CU; VGPR 44 <= cap 64).
__global__ __launch_bounds__(512, 8) void knn_kernel(const float* __restrict__ pos,
                                                     const float* __restrict__ pos_skip,
                                                     const float* __restrict__ W1,
                                                     __hip_bfloat16* __restrict__ W1T,
                                                     i32x4* __restrict__ idxo,
                                                     f32x4* __restrict__ wqo,
                                                     float* __restrict__ stats) {
#pragma clang fp contract(off)
    const int blk = blockIdx.x;
    if (blk >= KNN_BLOCKS) {
        const int e = blk - KNN_BLOCKS;
        if (e < WT_BLOCKS) {
            const int r  = e * 32 + (threadIdx.x >> 4);
            const int c0 = threadIdx.x & 15;
#pragma unroll
            for (int k = 0; k < DIN / 16; ++k) {
                int c = c0 + k * 16;
                W1T[(size_t)r * DIN + c] = __float2bfloat16(W1[(size_t)c * HID + r]);
            }
        } else {
            for (int i = threadIdx.x; i < 4 * HID; i += 512) stats[i] = 0.0f;
        }
        return;
    }
    __shared__ float4 sp[NSRC];
    const int t0 = blk * TGT_PER_BLK;
    const int b  = t0 / NTGT;
    const float* ps = pos + (size_t)b * NSRC * 3;
    for (int j = threadIdx.x; j < NSRC; j += 512) {
        float X = ps[j * 3 + 0], Y = ps[j * 3 + 1], Z = ps[j * 3 + 2];
        float s2 = ((X * X) + (Y * Y)) + (Z * Z);
        sp[j] = make_float4(X, Y, Z, s2);
    }
    __syncthreads();
    const int g  = threadIdx.x >> 5;   // target group 0..15
    const int s  = threadIdx.x & 31;   // sub-lane 0..31
    const int tr = t0 + g;
    const float px = pos_skip[tr * 3 + 0], py = pos_skip[tr * 3 + 1], pz = pos_skip[tr * 3 + 2];
    const float pt2 = ((px * px) + (py * py)) + (pz * pz);
    const f32x2 px2 = {px, px}, py2 = {py, py}, pz2 = {pz, pz}, ptv = {pt2, pt2};
    const f32x2 two = {2.0f, 2.0f};

    // ---- pass 1: 3 smallest values via TWO independent chains (halved dep chain) ----
    float a0 = 3e38f, a1 = 3e38f, a2v = 3e38f;   // chain A: j1-half
    float b0 = 3e38f, b1 = 3e38f, b2v = 3e38f;   // chain B: j2-half
#pragma unroll
    for (int k = 0; k < NSRC / 64; ++k) {
        const int j1 = k * 64 + s;
        const int j2 = j1 + 32;
        float4 sa = sp[j1];
        float4 sb = sp[j2];
        f32x2 vx = {sa.x, sb.x}, vy = {sa.y, sb.y}, vz = {sa.z, sb.z}, vw = {sa.w, sb.w};
        // exact replica of reference's expanded formula: (pt2 + ps2) - 2*dot, contract(off) => no FMA
        f32x2 dot = ((px2 * vx) + (py2 * vy)) + (pz2 * vz);
        f32x2 d2v = (ptv + vw) - (two * dot);
        {
            float d = d2v.x;
            float n0 = fminf(a0, d);
            float n1 = __builtin_amdgcn_fmed3f(a0, a1, d);
            float n2 = fminf(a2v, fmaxf(a1, d));
            a0 = n0; a1 = n1; a2v = n2;
        }
        {
            float d = d2v.y;
            float n0 = fminf(b0, d);
            float n1 = __builtin_amdgcn_fmed3f(b0, b1, d);
            float n2 = fminf(b2v, fmaxf(b1, d));
            b0 = n0; b1 = n1; b2v = n2;
        }
    }
    // merge the two sorted triples (same network as butterfly body, R8-proven)
    {
        float minb = fminf(a1, b1);
        float maxa = fmaxf(a0, b0);
        float maxb = fmaxf(a1, b1);
        float minc = fminf(a2v, b2v);
        float n0 = fminf(a0, b0);
        float n1 = __builtin_amdgcn_fmed3f(a0, b0, minb);
        float n2 = __builtin_amdgcn_fmed3f(minb, maxa, fminf(maxb, minc));
        a0 = n0; a1 = n1; a2v = n2;
    }
    // value butterfly merge across 32 sub-lanes
#pragma unroll
    for (int m = 1; m <= 16; m <<= 1) {
        float oa = __shfl_xor(a0, m), ob = __shfl_xor(a1, m), oc = __shfl_xor(a2v, m);
        float minb = fminf(a1, ob);
        float maxa = fmaxf(a0, oa);
        float maxb = fmaxf(a1, ob);
        float minc = fminf(a2v, oc);
        float n0 = fminf(a0, oa);
        float n1 = __builtin_amdgcn_fmed3f(a0, oa, minb);
        float n2 = __builtin_amdgcn_fmed3f(minb, maxa, fminf(maxb, minc));
        a0 = n0; a1 = n1; a2v = n2;
    }
    const float cut = a2v;

    // ---- pass 2: recompute distances (bitwise-identical), skip non-hit iters ----
    float bd0 = 3e38f, bd1 = 3e38f, bd2 = 3e38f;
    int   bi0 = 0x7fffffff, bi1 = 0x7fffffff, bi2 = 0x7fffffff;
#pragma unroll
    for (int k = 0; k < NSRC / 64; ++k) {
        const int j1 = k * 64 + s;
        const int j2 = j1 + 32;
        float4 sa = sp[j1];
        float4 sb = sp[j2];
        f32x2 vx = {sa.x, sb.x}, vy = {sa.y, sb.y}, vz = {sa.z, sb.z}, vw = {sa.w, sb.w};
        f32x2 dot = ((px2 * vx) + (py2 * vy)) + (pz2 * vz);
        f32x2 d2v = (ptv + vw) - (two * dot);
        if (__any(d2v.x <= cut) || __any(d2v.y <= cut)) {
            // all lanes insert both visits in order; junk (> cut) never survives the lex merge
#pragma unroll
            for (int h = 0; h < 2; ++h) {
                float d2 = h == 0 ? d2v.x : d2v.y;
                int   j  = h == 0 ? j1 : j2;
                bool c0 = d2 < bd0, c1 = d2 < bd1, c2 = d2 < bd2;
                bd2 = c1 ? bd1 : (c2 ? d2 : bd2);  bi2 = c1 ? bi1 : (c2 ? j : bi2);
                bd1 = c0 ? bd0 : (c1 ? d2 : bd1);  bi1 = c0 ? bi0 : (c1 ? j : bi1);
                bd0 = c0 ? d2  : bd0;              bi0 = c0 ? j  : bi0;
            }
        }
    }
    // lex (d, idx) butterfly merge -- preserves reference top_k smaller-index tie-break
#pragma unroll
    for (int m = 1; m <= 16; m <<= 1) {
        float od0 = __shfl_xor(bd0, m), od1 = __shfl_xor(bd1, m), od2 = __shfl_xor(bd2, m);
        int   oi0 = __shfl_xor(bi0, m), oi1 = __shfl_xor(bi1, m), oi2 = __shfl_xor(bi2, m);
#pragma unroll
        for (int e = 0; e < 3; ++e) {
            float d = e == 0 ? od0 : (e == 1 ? od1 : od2);
            int   i = e == 0 ? oi0 : (e == 1 ? oi1 : oi2);
            bool c0 = (d < bd0) || (d == bd0 && i < bi0);
            bool c1 = (d < bd1) || (d == bd1 && i < bi1);
            bool c2 = (d < bd2) || (d == bd2 && i < bi2);
            bd2 = c1 ? bd1 : (c2 ? d : bd2);  bi2 = c1 ? bi1 : (c2 ? i : bi2);
            bd1 = c0 ? bd0 : (c1 ? d : bd1);  bi1 = c0 ? bi0 : (c1 ? i : bi1);
            bd0 = c0 ? d   : bd0;             bi0 = c0 ? i  : bi0;
        }
    }
    if (s == 0) {
        float w0 = 1.0f / fmaxf(bd0, 1e-16f);
        float w1 = 1.0f / fmaxf(bd1, 1e-16f);
        float w2 = 1.0f / fmaxf(bd2, 1e-16f);
        float inv = 1.0f / ((w0 + w1) + w2);
        idxo[tr] = i32x4{bi0, bi1, bi2, 0};
        wqo[tr]  = f32x4{w0 * inv, w1 * inv, w2 * inv, 0.0f};
    }
}

// ================= ZS (R10-exact): Z = bf16(x)@W1_top (64 blks), S = bf16(xs)@W1_bot (256 blks) =================
__global__ __launch_bounds__(256, 1) void zs_kernel(const float* __restrict__ x,
                                                    const float* __restrict__ xs,
                                                    const __hip_bfloat16* __restrict__ W1T,
                                                    __hip_bfloat16* __restrict__ Z,
                                                    __hip_bfloat16* __restrict__ S) {
    __shared__ short As[128 * LDS_STRIDE];
    const int blk = blockIdx.x;
    const float* A;
    __hip_bfloat16* out;
    int K, koff, m0;
    if (blk < 64) { A = x;  out = Z; K = 256; koff = 0;   m0 = blk * 128; }
    else          { A = xs; out = S; K = 128; koff = 256; m0 = (blk - 64) * 128; }
    const int t = threadIdx.x;
    const int wid = t >> 6, lane = t & 63;
    const int wr = wid & 1, wcq = wid >> 1;
    const int l15 = lane & 15, l4 = lane >> 4;
    const int arow = t >> 1, ac16 = (t & 1) * 16;   // each thread: 16 fp32 -> 16 bf16
    const short* Wsh = (const short*)W1T;
    f32x4 acc[4][8] = {};
    for (int kt = 0; kt < K / 32; ++kt) {
        const float* src = A + (size_t)(m0 + arow) * K + kt * 32 + ac16;
        float4 f0 = *(const float4*)(src);
        float4 f1 = *(const float4*)(src + 4);
        float4 f2 = *(const float4*)(src + 8);
        float4 f3 = *(const float4*)(src + 12);
        short8 s0 = {f2bf(f0.x), f2bf(f0.y), f2bf(f0.z), f2bf(f0.w),
                     f2bf(f1.x), f2bf(f1.y), f2bf(f1.z), f2bf(f1.w)};
        short8 s1 = {f2bf(f2.x), f2bf(f2.y), f2bf(f2.z), f2bf(f2.w),
                     f2bf(f3.x), f2bf(f3.y), f2bf(f3.z), f2bf(f3.w)};
        __syncthreads();
        *(short8*)(&As[arow * LDS_STRIDE + ac16])     = s0;
        *(short8*)(&As[arow * LDS_STRIDE + ac16 + 8]) = s1;
        __syncthreads();
        short8 af[4], bfr[8];
#pragma unroll
        for (int mi = 0; mi < 4; ++mi)
            af[mi] = *(const short8*)(&As[(wr * 64 + mi * 16 + l15) * LDS_STRIDE + l4 * 8]);
#pragma unroll
        for (int ni = 0; ni < 8; ++ni)
            bfr[ni] = *(const short8*)(Wsh + (size_t)(wcq * 128 + ni * 16 + l15) * DIN + koff + kt * 32 + l4 * 8);
#pragma unroll
        for (int mi = 0; mi < 4; ++mi)
#pragma unroll
            for (int ni = 0; ni < 8; ++ni)
                acc[mi][ni] = __builtin_amdgcn_mfma_f32_16x16x32_bf16(af[mi], bfr[ni], acc[mi][ni], 0, 0, 0);
    }
#pragma unroll
    for (int mi = 0; mi < 4; ++mi)
#pragma unroll
        for (int r = 0; r < 4; ++r) {
            int rowg = m0 + wr * 64 + mi * 16 + l4 * 4 + r;
#pragma unroll
            for (int ni = 0; ni < 8; ++ni) {
                int col = wcq * 128 + ni * 16 + l15;
                out[(size_t)rowg * HID + col] = __float2bfloat16(acc[mi][ni][r]);
            }
        }
}

// ================= interp (R10-exact): one row-chunk per thread, no loop =================
__global__ __launch_bounds__(256) void interp_kernel(const __hip_bfloat16* __restrict__ Z,
                                                     const __hip_bfloat16* __restrict__ S,
                                                     const i32x4* __restrict__ idxo,
                                                     const f32x4* __restrict__ wqo,
                                                     const float* __restrict__ b1,
                                                     __hip_bfloat16* __restrict__ H1) {
    const int t = blockIdx.x * 256 + threadIdx.x;   // grid covers MROWS*32 exactly
    const int r = t >> 5;
    const int c = (t & 31) * 8;
    i32x4 id = idxo[r];
    f32x4 wq = wqo[r];
    const int zb = (r >> 13) << 11;   // batch * NSRC
    const short* Zs = (const short*)Z;
    short8 z0 = *(const short8*)(Zs + (size_t)(zb + id.x) * HID + c);
    short8 z1 = *(const short8*)(Zs + (size_t)(zb + id.y) * HID + c);
    short8 z2 = *(const short8*)(Zs + (size_t)(zb + id.z) * HID + c);
    short8 sv = *(const short8*)((const short*)S + (size_t)r * HID + c);
    f32x4 b0 = *(const f32x4*)(b1 + c);
    f32x4 b4 = *(const f32x4*)(b1 + c + 4);
    short8 ho;
#pragma unroll
    for (int e = 0; e < 8; ++e) {
        float bb = e < 4 ? b0[e & 3] : b4[e & 3];
        float v = wq.x * bf2f(z0[e]) + wq.y * bf2f(z1[e]) + wq.z * bf2f(z2[e])
                  + bf2f(sv[e]) + bb;
        ho[e] = f2bf(fmaxf(v, 0.0f));
    }
    *(short8*)((short*)H1 + (size_t)r * HID + c) = ho;
}

// ================= stats1 (R10-exact): column sum/sumsq of H1 =================
__global__ __launch_bounds__(256) void stats1_kernel(const __hip_bfloat16* __restrict__ H1,
                                                     float* __restrict__ sum1,
                                                     float* __restrict__ sq1) {
    const int c  = threadIdx.x;
    const int r0 = blockIdx.x * (MROWS / 128);
    const short* Hs = (const short*)H1;
    float s = 0.0f, q = 0.0f;
#pragma unroll 8
    for (int r = 0; r < MROWS / 128; ++r) {
        float v = bf2f(Hs[(size_t)(r0 + r) * HID + c]);
        s += v;
        q += v * v;
    }
    atomicAdd(&sum1[c], s);
    atomicAdd(&sq1[c], q);
}

// ================= GEMM2 (R10-exact): out = relu(A@W + bias) bf16, column stats =================
template <int K>
__global__ __launch_bounds__(256, 1) void gemm_kernel(const __hip_bfloat16* __restrict__ A,
                                                      const __hip_bfloat16* __restrict__ WT,
                                                      const float* __restrict__ bias,
                                                      __hip_bfloat16* __restrict__ outp,
                                                      float* __restrict__ colsum,
                                                      float* __restrict__ colsq) {
    __shared__ short As[128 * LDS_STRIDE];
    const int t = threadIdx.x;
    const int m0 = blockIdx.x * 128;
    const int wid = t >> 6, lane = t & 63;
    const int wr = wid & 1, wcq = wid >> 1;
    const int l15 = lane & 15, l4 = lane >> 4;
    const int arow = t >> 1, acol8 = (t & 1) * 8;
    f32x4 acc[4][8] = {};
    const short* Ash = (const short*)A;
    const short* Wsh = (const short*)WT;
    for (int kt = 0; kt < K / 32; ++kt) {
        short8 v0 = *(const short8*)(Ash + (size_t)(m0 + arow) * K + kt * 32 + acol8);
        short8 v1 = *(const short8*)(Ash + (size_t)(m0 + arow) * K + kt * 32 + acol8 + 16);
        __syncthreads();
        *(short8*)(&As[arow * LDS_STRIDE + acol8]) = v0;
        *(short8*)(&As[arow * LDS_STRIDE + acol8 + 16]) = v1;
        __syncthreads();
        short8 af[4], bfr[8];
#pragma unroll
        for (int mi = 0; mi < 4; ++mi)
            af[mi] = *(const short8*)(&As[(wr * 64 + mi * 16 + l15) * LDS_STRIDE + l4 * 8]);
#pragma unroll
        for (int ni = 0; ni < 8; ++ni)
            bfr[ni] = *(const short8*)(Wsh + (size_t)(wcq * 128 + ni * 16 + l15) * K + kt * 32 + l4 * 8);
#pragma unroll
        for (int mi = 0; mi < 4; ++mi)
#pragma unroll
            for (int ni = 0; ni < 8; ++ni)
                acc[mi][ni] = __builtin_amdgcn_mfma_f32_16x16x32_bf16(af[mi], bfr[ni], acc[mi][ni], 0, 0, 0);
    }
    float bv[8];
    int col[8];
#pragma unroll
    for (int ni = 0; ni < 8; ++ni) {
        col[ni] = wcq * 128 + ni * 16 + l15;
        bv[ni] = bias[col[ni]];
    }
    float csum[8] = {}, csq[8] = {};
#pragma unroll
    for (int mi = 0; mi < 4; ++mi) {
#pragma unroll
        for (int r = 0; r < 4; ++r) {
            int rowg = m0 + wr * 64 + mi * 16 + l4 * 4 + r;
#pragma unroll
            for (int ni = 0; ni < 8; ++ni) {
                float v = fmaxf(acc[mi][ni][r] + bv[ni], 0.0f);
                outp[(size_t)rowg * HID + col[ni]] = __float2bfloat16(v);
                csum[ni] += v;
                csq[ni] += v * v;
            }
        }
    }
#pragma unroll
    for (int ni = 0; ni < 8; ++ni) {
        float sv = csum[ni], q = csq[ni];
        sv += __shfl_xor(sv, 16); sv += __shfl_xor(sv, 32);
        q  += __shfl_xor(q, 16);  q  += __shfl_xor(q, 32);
        if (l4 == 0) {
            atomicAdd(&colsum[col[ni]], sv);
            atomicAdd(&colsq[col[ni]], q);
        }
    }
}

// ================= finalize BN1 + fold into W2 =================
__global__ __launch_bounds__(256) void foldw2_kernel(const float* __restrict__ W2,
                                                     const float* __restrict__ b2,
                                                     const float* __restrict__ sum1,
                                                     const float* __restrict__ sq1,
                                                     const float* __restrict__ g1,
                                                     const float* __restrict__ be1,
                                                     __hip_bfloat16* __restrict__ W2T,
                                                     float* __restrict__ bias2f) {
    __shared__ float red[256];
    const int n = blockIdx.x, k = threadIdx.x;
    float mu  = sum1[k] * (1.0f / MROWS);
    float var = sq1[k] * (1.0f / MROWS) - mu * mu;
    float scv = g1[k] / sqrtf(var + 1e-5f);
    float shv = be1[k] - mu * scv;
    float v = W2[(size_t)k * HID + n];
    W2T[(size_t)n * HID + k] = __float2bfloat16(scv * v);
    red[k] = shv * v;
    __syncthreads();
    for (int s = 128; s > 0; s >>= 1) {
        if (k < s) red[k] += red[k + s];
        __syncthreads();
    }
    if (k == 0) bias2f[n] = b2[n] + red[0];
}

// ================= BN2 (R10-exact): read h2 (bf16), apply scale/shift, write fp32 =================
__global__ __launch_bounds__(256) void bn2_kernel(const __hip_bfloat16* __restrict__ h2,
                                                  const float* __restrict__ sum2,
                                                  const float* __restrict__ sq2,
                                                  const float* __restrict__ g2,
                                                  const float* __restrict__ be2,
                                                  float* __restrict__ out) {
    __shared__ float lsc[HID], lsh[HID];
    {
        int c = threadIdx.x;
        float mu  = sum2[c] * (1.0f / MROWS);
        float var = sq2[c] * (1.0f / MROWS) - mu * mu;
        float scv = g2[c] / sqrtf(var + 1e-5f);
        lsc[c] = scv;
        lsh[c] = be2[c] - mu * scv;
    }
    __syncthreads();
    int idx = blockIdx.x * blockDim.x + threadIdx.x;
    const int total = MROWS * HID / 8;
    for (; idx < total; idx += gridDim.x * blockDim.x) {
        short8 v = *(const short8*)(h2 + (size_t)idx * 8);
        int c = (idx * 8) & (HID - 1);
        f32x8 o;
#pragma unroll
        for (int e = 0; e < 8; ++e) {
            float f = bf2f(v[e]);
            o[e] = lsc[c + e] * f + lsh[c + e];
        }
        *(f32x8*)(out + (size_t)idx * 8) = o;
    }
}

extern "C" void kernel_launch(void* const* d_in, const int* in_sizes, int n_in,
                              void* d_out, int out_size, void* d_ws, size_t ws_size,
                              hipStream_t stream) {
    const float* x    = (const float*)d_in[0];
    const float* pos  = (const float*)d_in[1];
    const float* xs   = (const float*)d_in[3];
    const float* poss = (const float*)d_in[4];
    const float* W1   = (const float*)d_in[6];
    const float* b1   = (const float*)d_in[7];
    const float* g1   = (const float*)d_in[8];
    const float* be1  = (const float*)d_in[9];
    const float* W2   = (const float*)d_in[10];
    const float* b2   = (const float*)d_in[11];
    const float* g2   = (const float*)d_in[12];
    const float* be2  = (const float*)d_in[13];

    char* ws = (char*)d_ws;
    size_t off = 0;
    auto alloc = [&](size_t bytes) -> void* {
        void* p = ws + off;
        off += (bytes + 255) & ~(size_t)255;
        return p;
    };
    __hip_bfloat16* W1T   = (__hip_bfloat16*)alloc((size_t)HID * DIN * 2);
    __hip_bfloat16* W2T   = (__hip_bfloat16*)alloc((size_t)HID * HID * 2);
    float*          stats = (float*)alloc(4 * HID * sizeof(float));
    float *sum1 = stats, *sq1 = stats + HID, *sum2 = stats + 2 * HID, *sq2 = stats + 3 * HID;
    float*          bias2f = (float*)alloc(HID * sizeof(float));
    i32x4*          idxo  = (i32x4*)alloc((size_t)MROWS * 16);
    f32x4*          wqo   = (f32x4*)alloc((size_t)MROWS * 16);
    __hip_bfloat16* Z     = (__hip_bfloat16*)alloc((size_t)BATCH * NSRC * HID * 2);  // 4 MB
    __hip_bfloat16* S     = (__hip_bfloat16*)alloc((size_t)MROWS * HID * 2);         // 16 MB
    __hip_bfloat16* H1    = (__hip_bfloat16*)alloc((size_t)MROWS * HID * 2);         // 16 MB
    __hip_bfloat16* H2    = S;  // S dead after interp_kernel; reuse for gemm2 output

    knn_kernel<<<KNN_BLOCKS + WT_BLOCKS + 1, 512, 0, stream>>>(pos, poss, W1, W1T, idxo, wqo, stats);
    zs_kernel<<<64 + MROWS / 128, 256, 0, stream>>>(x, xs, W1T, Z, S);
    interp_kernel<<<MROWS * 32 / 256, 256, 0, stream>>>(Z, S, idxo, wqo, b1, H1);
    stats1_kernel<<<128, 256, 0, stream>>>(H1, sum1, sq1);
    foldw2_kernel<<<HID, 256, 0, stream>>>(W2, b2, sum1, sq1, g1, be1, W2T, bias2f);
    gemm_kernel<HID><<<MROWS / 128, 256, 0, stream>>>(H1, W2T, bias2f, H2, sum2, sq2);
    bn2_kernel<<<1024, 256, 0, stream>>>(H2, sum2, sq2, g2, be2, (float*)d_out);
}

// Round 15
// 126.862 us; speedup vs baseline: 1.1400x; 1.1400x over previous
//
#include <hip/hip_runtime.h>
#include <hip/hip_bf16.h>

typedef __attribute__((ext_vector_type(8))) short short8;
typedef __attribute__((ext_vector_type(4))) int   i32x4;
typedef __attribute__((ext_vector_type(4))) float f32x4;
typedef __attribute__((ext_vector_type(2))) float f32x2;
typedef __attribute__((ext_vector_type(8))) float f32x8;

constexpr int BATCH  = 4;
constexpr int NSRC   = 2048;
constexpr int NTGT   = 8192;
constexpr int C_IN   = 256;
constexpr int C_SKIP = 128;
constexpr int DIN    = 384;   // C_IN + C_SKIP
constexpr int HID    = 256;
constexpr int MROWS  = BATCH * NTGT;  // 32768

constexpr int TGT_PER_BLK = 16;
constexpr int KNN_BLOCKS  = MROWS / TGT_PER_BLK;  // 2048
constexpr int WT_BLOCKS   = 8;                    // W1 transpose helper blocks
constexpr int LDS_STRIDE  = 36;                   // GEMM A-tile pad
constexpr int NPART       = 64;                   // stats1 partial buffers (atomic chain = 4096/64)

__device__ __forceinline__ short f2bf(float v) {
    __hip_bfloat16 h = __float2bfloat16(v);
    return (short)__builtin_bit_cast(unsigned short, h);
}
__device__ __forceinline__ float bf2f(short s) {
    return __uint_as_float(((unsigned)(unsigned short)s) << 16);
}

// ================= KNN (R13-exact, frozen): two-pass with register-cached distances =================
// R14 lesson: (512,8) VGPR-cap-64 codegen issued ~50% more instructions; (512,2) is optimal.
__global__ __launch_bounds__(512, 2) void knn_kernel(const float* __restrict__ pos,
                                                     const float* __restrict__ pos_skip,
                                                     const float* __restrict__ W1,
                                                     __hip_bfloat16* __restrict__ W1T,
                                                     i32x4* __restrict__ idxo,
                                                     f32x4* __restrict__ wqo,
                                                     float* __restrict__ stats,
                                                     float* __restrict__ partials) {
#pragma clang fp contract(off)
    const int blk = blockIdx.x;
    if (blk >= KNN_BLOCKS) {
        const int e = blk - KNN_BLOCKS;
        if (e < WT_BLOCKS) {
            const int r  = e * 32 + (threadIdx.x >> 4);
            const int c0 = threadIdx.x & 15;
#pragma unroll
            for (int k = 0; k < DIN / 16; ++k) {
                int c = c0 + k * 16;
                W1T[(size_t)r * DIN + c] = __float2bfloat16(W1[(size_t)c * HID + r]);
            }
        } else {
            for (int i = threadIdx.x; i < 4 * HID; i += 512) stats[i] = 0.0f;
            for (int i = threadIdx.x; i < 2 * NPART * HID; i += 512) partials[i] = 0.0f;
        }
        return;
    }
    __shared__ float4 sp[NSRC];
    const int t0 = blk * TGT_PER_BLK;
    const int b  = t0 / NTGT;
    const float* ps = pos + (size_t)b * NSRC * 3;
    for (int j = threadIdx.x; j < NSRC; j += 512) {
        float X = ps[j * 3 + 0], Y = ps[j * 3 + 1], Z = ps[j * 3 + 2];
        float s2 = ((X * X) + (Y * Y)) + (Z * Z);
        sp[j] = make_float4(X, Y, Z, s2);
    }
    __syncthreads();
    const int g  = threadIdx.x >> 5;   // target group 0..15
    const int s  = threadIdx.x & 31;   // sub-lane 0..31
    const int tr = t0 + g;
    const float px = pos_skip[tr * 3 + 0], py = pos_skip[tr * 3 + 1], pz = pos_skip[tr * 3 + 2];
    const float pt2 = ((px * px) + (py * py)) + (pz * pz);
    const f32x2 px2 = {px, px}, py2 = {py, py}, pz2 = {pz, pz}, ptv = {pt2, pt2};
    const f32x2 two = {2.0f, 2.0f};

    // ---- pass 1: distances -> registers; 3 smallest values only ----
    float dreg[64];
    float a0 = 3e38f, a1 = 3e38f, a2 = 3e38f;
#pragma unroll
    for (int k = 0; k < NSRC / 64; ++k) {
        const int j1 = k * 64 + s;
        const int j2 = j1 + 32;
        float4 sa = sp[j1];
        float4 sb = sp[j2];
        f32x2 vx = {sa.x, sb.x}, vy = {sa.y, sb.y}, vz = {sa.z, sb.z}, vw = {sa.w, sb.w};
        // exact replica of reference's expanded formula: (pt2 + ps2) - 2*dot, contract(off) => no FMA
        f32x2 dot = ((px2 * vx) + (py2 * vy)) + (pz2 * vz);
        f32x2 d2v = (ptv + vw) - (two * dot);
        dreg[2 * k]     = d2v.x;
        dreg[2 * k + 1] = d2v.y;
#pragma unroll
        for (int h = 0; h < 2; ++h) {
            float d = h == 0 ? d2v.x : d2v.y;
            float n0 = fminf(a0, d);
            float n1 = __builtin_amdgcn_fmed3f(a0, a1, d);
            float n2 = fminf(a2, fmaxf(a1, d));
            a0 = n0; a1 = n1; a2 = n2;
        }
    }
    // value butterfly merge (top-3 of two sorted triples)
#pragma unroll
    for (int m = 1; m <= 16; m <<= 1) {
        float oa = __shfl_xor(a0, m), ob = __shfl_xor(a1, m), oc = __shfl_xor(a2, m);
        float minb = fminf(a1, ob);
        float maxa = fmaxf(a0, oa);
        float maxb = fmaxf(a1, ob);
        float minc = fminf(a2, oc);
        float n0 = fminf(a0, oa);
        float n1 = __builtin_amdgcn_fmed3f(a0, oa, minb);
        float n2 = __builtin_amdgcn_fmed3f(minb, maxa, fminf(maxb, minc));
        a0 = n0; a1 = n1; a2 = n2;
    }

    // ---- pass 2: index recovery from register-cached distances ----
    float bd0 = 3e38f, bd1 = 3e38f, bd2 = 3e38f;
    int   bi0 = 0x7fffffff, bi1 = 0x7fffffff, bi2 = 0x7fffffff;
#pragma unroll
    for (int i = 0; i < 64; ++i) {
        float d2 = dreg[i];
        if (__any(d2 <= a2)) {   // uniform branch: s_cbranch_vccz skip on miss-iters
            // all lanes insert; junk (> a2) provably never survives the lex merge
            const int j = (i >> 1) * 64 + ((i & 1) << 5) + s;  // visit order == one-pass scan
            bool c0 = d2 < bd0, c1 = d2 < bd1, c2 = d2 < bd2;
            bd2 = c1 ? bd1 : (c2 ? d2 : bd2);  bi2 = c1 ? bi1 : (c2 ? j : bi2);
            bd1 = c0 ? bd0 : (c1 ? d2 : bd1);  bi1 = c0 ? bi0 : (c1 ? j : bi1);
            bd0 = c0 ? d2  : bd0;              bi0 = c0 ? j  : bi0;
        }
    }
    // lex (d, idx) butterfly merge -- preserves reference top_k smaller-index tie-break
#pragma unroll
    for (int m = 1; m <= 16; m <<= 1) {
        float od0 = __shfl_xor(bd0, m), od1 = __shfl_xor(bd1, m), od2 = __shfl_xor(bd2, m);
        int   oi0 = __shfl_xor(bi0, m), oi1 = __shfl_xor(bi1, m), oi2 = __shfl_xor(bi2, m);
#pragma unroll
        for (int e = 0; e < 3; ++e) {
            float d = e == 0 ? od0 : (e == 1 ? od1 : od2);
            int   i = e == 0 ? oi0 : (e == 1 ? oi1 : oi2);
            bool c0 = (d < bd0) || (d == bd0 && i < bi0);
            bool c1 = (d < bd1) || (d == bd1 && i < bi1);
            bool c2 = (d < bd2) || (d == bd2 && i < bi2);
            bd2 = c1 ? bd1 : (c2 ? d : bd2);  bi2 = c1 ? bi1 : (c2 ? i : bi2);
            bd1 = c0 ? bd0 : (c1 ? d : bd1);  bi1 = c0 ? bi0 : (c1 ? i : bi1);
            bd0 = c0 ? d   : bd0;             bi0 = c0 ? i  : bi0;
        }
    }
    if (s == 0) {
        float w0 = 1.0f / fmaxf(bd0, 1e-16f);
        float w1 = 1.0f / fmaxf(bd1, 1e-16f);
        float w2 = 1.0f / fmaxf(bd2, 1e-16f);
        float inv = 1.0f / ((w0 + w1) + w2);
        idxo[tr] = i32x4{bi0, bi1, bi2, 0};
        wqo[tr]  = f32x4{w0 * inv, w1 * inv, w2 * inv, 0.0f};
    }
}

// ================= ZS (R10-exact): Z = bf16(x)@W1_top (64 blks), S = bf16(xs)@W1_bot (256 blks) =================
__global__ __launch_bounds__(256, 1) void zs_kernel(const float* __restrict__ x,
                                                    const float* __restrict__ xs,
                                                    const __hip_bfloat16* __restrict__ W1T,
                                                    __hip_bfloat16* __restrict__ Z,
                                                    __hip_bfloat16* __restrict__ S) {
    __shared__ short As[128 * LDS_STRIDE];
    const int blk = blockIdx.x;
    const float* A;
    __hip_bfloat16* out;
    int K, koff, m0;
    if (blk < 64) { A = x;  out = Z; K = 256; koff = 0;   m0 = blk * 128; }
    else          { A = xs; out = S; K = 128; koff = 256; m0 = (blk - 64) * 128; }
    const int t = threadIdx.x;
    const int wid = t >> 6, lane = t & 63;
    const int wr = wid & 1, wcq = wid >> 1;
    const int l15 = lane & 15, l4 = lane >> 4;
    const int arow = t >> 1, ac16 = (t & 1) * 16;   // each thread: 16 fp32 -> 16 bf16
    const short* Wsh = (const short*)W1T;
    f32x4 acc[4][8] = {};
    for (int kt = 0; kt < K / 32; ++kt) {
        const float* src = A + (size_t)(m0 + arow) * K + kt * 32 + ac16;
        float4 f0 = *(const float4*)(src);
        float4 f1 = *(const float4*)(src + 4);
        float4 f2 = *(const float4*)(src + 8);
        float4 f3 = *(const float4*)(src + 12);
        short8 s0 = {f2bf(f0.x), f2bf(f0.y), f2bf(f0.z), f2bf(f0.w),
                     f2bf(f1.x), f2bf(f1.y), f2bf(f1.z), f2bf(f1.w)};
        short8 s1 = {f2bf(f2.x), f2bf(f2.y), f2bf(f2.z), f2bf(f2.w),
                     f2bf(f3.x), f2bf(f3.y), f2bf(f3.z), f2bf(f3.w)};
        __syncthreads();
        *(short8*)(&As[arow * LDS_STRIDE + ac16])     = s0;
        *(short8*)(&As[arow * LDS_STRIDE + ac16 + 8]) = s1;
        __syncthreads();
        short8 af[4], bfr[8];
#pragma unroll
        for (int mi = 0; mi < 4; ++mi)
            af[mi] = *(const short8*)(&As[(wr * 64 + mi * 16 + l15) * LDS_STRIDE + l4 * 8]);
#pragma unroll
        for (int ni = 0; ni < 8; ++ni)
            bfr[ni] = *(const short8*)(Wsh + (size_t)(wcq * 128 + ni * 16 + l15) * DIN + koff + kt * 32 + l4 * 8);
#pragma unroll
        for (int mi = 0; mi < 4; ++mi)
#pragma unroll
            for (int ni = 0; ni < 8; ++ni)
                acc[mi][ni] = __builtin_amdgcn_mfma_f32_16x16x32_bf16(af[mi], bfr[ni], acc[mi][ni], 0, 0, 0);
    }
#pragma unroll
    for (int mi = 0; mi < 4; ++mi)
#pragma unroll
        for (int r = 0; r < 4; ++r) {
            int rowg = m0 + wr * 64 + mi * 16 + l4 * 4 + r;
#pragma unroll
            for (int ni = 0; ni < 8; ++ni) {
                int col = wcq * 128 + ni * 16 + l15;
                out[(size_t)rowg * HID + col] = __float2bfloat16(acc[mi][ni][r]);
            }
        }
}

// ================= interp + fused stats (64 partial buffers): h1 = relu(..), partials += colsum =================
// One row-chunk per thread (R10-proven); block LDS-reduces its 8 rows then 1 atomic/col into
// partial[blk % 64] -> per-address chain 4096/64 = 64 (R11's fused version had 1024: atomic storm).
__global__ __launch_bounds__(256) void interp_kernel(const __hip_bfloat16* __restrict__ Z,
                                                     const __hip_bfloat16* __restrict__ S,
                                                     const i32x4* __restrict__ idxo,
                                                     const f32x4* __restrict__ wqo,
                                                     const float* __restrict__ b1,
                                                     __hip_bfloat16* __restrict__ H1,
                                                     float* __restrict__ partials) {
    __shared__ float ls[8][HID], lq[8][HID];
    const int t = blockIdx.x * 256 + threadIdx.x;   // grid covers MROWS*32 exactly
    const int r = t >> 5;
    const int c = (t & 31) * 8;
    i32x4 id = idxo[r];
    f32x4 wq = wqo[r];
    const int zb = (r >> 13) << 11;   // batch * NSRC
    const short* Zs = (const short*)Z;
    short8 z0 = *(const short8*)(Zs + (size_t)(zb + id.x) * HID + c);
    short8 z1 = *(const short8*)(Zs + (size_t)(zb + id.y) * HID + c);
    short8 z2 = *(const short8*)(Zs + (size_t)(zb + id.z) * HID + c);
    short8 sv = *(const short8*)((const short*)S + (size_t)r * HID + c);
    f32x4 b0 = *(const f32x4*)(b1 + c);
    f32x4 b4 = *(const f32x4*)(b1 + c + 4);
    short8 ho;
    f32x8 hv;
#pragma unroll
    for (int e = 0; e < 8; ++e) {
        float bb = e < 4 ? b0[e & 3] : b4[e & 3];
        float v = wq.x * bf2f(z0[e]) + wq.y * bf2f(z1[e]) + wq.z * bf2f(z2[e])
                  + bf2f(sv[e]) + bb;
        v = fmaxf(v, 0.0f);
        hv[e] = v;
        ho[e] = f2bf(v);
    }
    *(short8*)((short*)H1 + (size_t)r * HID + c) = ho;
    // ---- fused stats: LDS reduce over the block's 8 rows, then 1 atomic/col ----
    const int grp = threadIdx.x >> 5;
#pragma unroll
    for (int e = 0; e < 8; ++e) {
        ls[grp][c + e] = hv[e];
        lq[grp][c + e] = hv[e] * hv[e];
    }
    __syncthreads();
    const int tc = threadIdx.x;   // column 0..255
    float s_ = 0.0f, q_ = 0.0f;
#pragma unroll
    for (int g2 = 0; g2 < 8; ++g2) { s_ += ls[g2][tc]; q_ += lq[g2][tc]; }
    float* pS = partials + (size_t)(blockIdx.x & (NPART - 1)) * HID;
    float* pQ = partials + (size_t)NPART * HID + (size_t)(blockIdx.x & (NPART - 1)) * HID;
    atomicAdd(&pS[tc], s_);
    atomicAdd(&pQ[tc], q_);
}

// ================= finalize BN1 (reduce 64 partials) + fold into W2 =================
__global__ __launch_bounds__(256) void foldw2_kernel(const float* __restrict__ W2,
                                                     const float* __restrict__ b2,
                                                     const float* __restrict__ partials,
                                                     const float* __restrict__ g1,
                                                     const float* __restrict__ be1,
                                                     __hip_bfloat16* __restrict__ W2T,
                                                     float* __restrict__ bias2f) {
    __shared__ float red[256];
    const int n = blockIdx.x, k = threadIdx.x;
    float sm = 0.0f, qq = 0.0f;
#pragma unroll
    for (int p = 0; p < NPART; ++p) {
        sm += partials[(size_t)p * HID + k];
        qq += partials[(size_t)NPART * HID + (size_t)p * HID + k];
    }
    float mu  = sm * (1.0f / MROWS);
    float var = qq * (1.0f / MROWS) - mu * mu;
    float scv = g1[k] / sqrtf(var + 1e-5f);
    float shv = be1[k] - mu * scv;
    float v = W2[(size_t)k * HID + n];
    W2T[(size_t)n * HID + k] = __float2bfloat16(scv * v);
    red[k] = shv * v;
    __syncthreads();
    for (int s = 128; s > 0; s >>= 1) {
        if (k < s) red[k] += red[k + s];
        __syncthreads();
    }
    if (k == 0) bias2f[n] = b2[n] + red[0];
}

// ================= GEMM2 (R10-exact): out = relu(A@W + bias) bf16, column stats =================
template <int K>
__global__ __launch_bounds__(256, 1) void gemm_kernel(const __hip_bfloat16* __restrict__ A,
                                                      const __hip_bfloat16* __restrict__ WT,
                                                      const float* __restrict__ bias,
                                                      __hip_bfloat16* __restrict__ outp,
                                                      float* __restrict__ colsum,
                                                      float* __restrict__ colsq) {
    __shared__ short As[128 * LDS_STRIDE];
    const int t = threadIdx.x;
    const int m0 = blockIdx.x * 128;
    const int wid = t >> 6, lane = t & 63;
    const int wr = wid & 1, wcq = wid >> 1;
    const int l15 = lane & 15, l4 = lane >> 4;
    const int arow = t >> 1, acol8 = (t & 1) * 8;
    f32x4 acc[4][8] = {};
    const short* Ash = (const short*)A;
    const short* Wsh = (const short*)WT;
    for (int kt = 0; kt < K / 32; ++kt) {
        short8 v0 = *(const short8*)(Ash + (size_t)(m0 + arow) * K + kt * 32 + acol8);
        short8 v1 = *(const short8*)(Ash + (size_t)(m0 + arow) * K + kt * 32 + acol8 + 16);
        __syncthreads();
        *(short8*)(&As[arow * LDS_STRIDE + acol8]) = v0;
        *(short8*)(&As[arow * LDS_STRIDE + acol8 + 16]) = v1;
        __syncthreads();
        short8 af[4], bfr[8];
#pragma unroll
        for (int mi = 0; mi < 4; ++mi)
            af[mi] = *(const short8*)(&As[(wr * 64 + mi * 16 + l15) * LDS_STRIDE + l4 * 8]);
#pragma unroll
        for (int ni = 0; ni < 8; ++ni)
            bfr[ni] = *(const short8*)(Wsh + (size_t)(wcq * 128 + ni * 16 + l15) * K + kt * 32 + l4 * 8);
#pragma unroll
        for (int mi = 0; mi < 4; ++mi)
#pragma unroll
            for (int ni = 0; ni < 8; ++ni)
                acc[mi][ni] = __builtin_amdgcn_mfma_f32_16x16x32_bf16(af[mi], bfr[ni], acc[mi][ni], 0, 0, 0);
    }
    float bv[8];
    int col[8];
#pragma unroll
    for (int ni = 0; ni < 8; ++ni) {
        col[ni] = wcq * 128 + ni * 16 + l15;
        bv[ni] = bias[col[ni]];
    }
    float csum[8] = {}, csq[8] = {};
#pragma unroll
    for (int mi = 0; mi < 4; ++mi) {
#pragma unroll
        for (int r = 0; r < 4; ++r) {
            int rowg = m0 + wr * 64 + mi * 16 + l4 * 4 + r;
#pragma unroll
            for (int ni = 0; ni < 8; ++ni) {
                float v = fmaxf(acc[mi][ni][r] + bv[ni], 0.0f);
                outp[(size_t)rowg * HID + col[ni]] = __float2bfloat16(v);
                csum[ni] += v;
                csq[ni] += v * v;
            }
        }
    }
#pragma unroll
    for (int ni = 0; ni < 8; ++ni) {
        float sv = csum[ni], q = csq[ni];
        sv += __shfl_xor(sv, 16); sv += __shfl_xor(sv, 32);
        q  += __shfl_xor(q, 16);  q  += __shfl_xor(q, 32);
        if (l4 == 0) {
            atomicAdd(&colsum[col[ni]], sv);
            atomicAdd(&colsq[col[ni]], q);
        }
    }
}

// ================= BN2 (R10-exact): read h2 (bf16), apply scale/shift, write fp32 =================
__global__ __launch_bounds__(256) void bn2_kernel(const __hip_bfloat16* __restrict__ h2,
                                                  const float* __restrict__ sum2,
                                                  const float* __restrict__ sq2,
                                                  const float* __restrict__ g2,
                                                  const float* __restrict__ be2,
                                                  float* __restrict__ out) {
    __shared__ float lsc[HID], lsh[HID];
    {
        int c = threadIdx.x;
        float mu  = sum2[c] * (1.0f / MROWS);
        float var = sq2[c] * (1.0f / MROWS) - mu * mu;
        float scv = g2[c] / sqrtf(var + 1e-5f);
        lsc[c] = scv;
        lsh[c] = be2[c] - mu * scv;
    }
    __syncthreads();
    int idx = blockIdx.x * blockDim.x + threadIdx.x;
    const int total = MROWS * HID / 8;
    for (; idx < total; idx += gridDim.x * blockDim.x) {
        short8 v = *(const short8*)(h2 + (size_t)idx * 8);
        int c = (idx * 8) & (HID - 1);
        f32x8 o;
#pragma unroll
        for (int e = 0; e < 8; ++e) {
            float f = bf2f(v[e]);
            o[e] = lsc[c + e] * f + lsh[c + e];
        }
        *(f32x8*)(out + (size_t)idx * 8) = o;
    }
}

extern "C" void kernel_launch(void* const* d_in, const int* in_sizes, int n_in,
                              void* d_out, int out_size, void* d_ws, size_t ws_size,
                              hipStream_t stream) {
    const float* x    = (const float*)d_in[0];
    const float* pos  = (const float*)d_in[1];
    const float* xs   = (const float*)d_in[3];
    const float* poss = (const float*)d_in[4];
    const float* W1   = (const float*)d_in[6];
    const float* b1   = (const float*)d_in[7];
    const float* g1   = (const float*)d_in[8];
    const float* be1  = (const float*)d_in[9];
    const float* W2   = (const float*)d_in[10];
    const float* b2   = (const float*)d_in[11];
    const float* g2   = (const float*)d_in[12];
    const float* be2  = (const float*)d_in[13];

    char* ws = (char*)d_ws;
    size_t off = 0;
    auto alloc = [&](size_t bytes) -> void* {
        void* p = ws + off;
        off += (bytes + 255) & ~(size_t)255;
        return p;
    };
    __hip_bfloat16* W1T   = (__hip_bfloat16*)alloc((size_t)HID * DIN * 2);
    __hip_bfloat16* W2T   = (__hip_bfloat16*)alloc((size_t)HID * HID * 2);
    float*          stats = (float*)alloc(4 * HID * sizeof(float));
    float *sum2 = stats + 2 * HID, *sq2 = stats + 3 * HID;
    float*          partials = (float*)alloc(2 * NPART * HID * sizeof(float));  // 128 KB
    float*          bias2f = (float*)alloc(HID * sizeof(float));
    i32x4*          idxo  = (i32x4*)alloc((size_t)MROWS * 16);
    f32x4*          wqo   = (f32x4*)alloc((size_t)MROWS * 16);
    __hip_bfloat16* Z     = (__hip_bfloat16*)alloc((size_t)BATCH * NSRC * HID * 2);  // 4 MB
    __hip_bfloat16* S     = (__hip_bfloat16*)alloc((size_t)MROWS * HID * 2);         // 16 MB
    __hip_bfloat16* H1    = (__hip_bfloat16*)alloc((size_t)MROWS * HID * 2);         // 16 MB
    __hip_bfloat16* H2    = S;  // S dead after interp_kernel; reuse for gemm2 output

    knn_kernel<<<KNN_BLOCKS + WT_BLOCKS + 1, 512, 0, stream>>>(pos, poss, W1, W1T, idxo, wqo,
                                                               stats, partials);
    zs_kernel<<<64 + MROWS / 128, 256, 0, stream>>>(x, xs, W1T, Z, S);
    interp_kernel<<<MROWS * 32 / 256, 256, 0, stream>>>(Z, S, idxo, wqo, b1, H1, partials);
    foldw2_kernel<<<HID, 256, 0, stream>>>(W2, b2, partials, g1, be1, W2T, bias2f);
    gemm_kernel<HID><<<MROWS / 128, 256, 0, stream>>>(H1, W2T, bias2f, H2, sum2, sq2);
    bn2_kernel<<<1024, 256, 0, stream>>>(H2, sum2, sq2, g2, be2, (float*)d_out);
}